// Round 2
// baseline (186.996 us; speedup 1.0000x reference)
//
#include <hip/hip_runtime.h>
#include <math.h>

// RC thermal model: x' = A x + b0*To(t) + Bq, RK4 h=30, T=1e6 steps.
// Closed form per step: x_{t+1} = M x_t + c + al*To[t] + be*To[t+1].
// Contractive system (Re eig(A) ~ -1e-5/s): M^65536 ~ 3e-9, so cross-block
// prefix truncates to the 16 nearest predecessor aggregates -> no global scan.
// 3 kernels: setup (fp64 consts) -> fold_scan (block-local Hillis-Steele,
// publish per-block agg) -> fixup_expand (truncated lookback + bit-decomp
// prefix fixup + 8-step expansion + coalesced-ish row writes).

#define S_STEPS 999999      // T-1 recurrence steps
#define CH      8           // steps per chunk (per thread)
#define BLK     512         // threads per block
#define NB      256         // blocks: 256*512*8 = 1,048,576 >= S_STEPS
#define NLVL    9           // log2(BLK) scan levels
#define NLOOK   16          // lookback depth: M^(4096*16) ~ 3e-9, negligible

// ws float offsets
#define OFF_M   0           // 144  : M
#define OFF_C   144         // 12   : c
#define OFF_AL  156         // 12   : alpha
#define OFF_BE  168         // 12   : beta
#define OFF_P2  180         // 9*144: P2[l] = M^(8*2^l), l=0..8
#define OFF_PD  1476        // 16*144: Pd[j] = M^(4096*j), j=0..15 (Pd[0]=I)
#define OFF_AGG 3780        // 256*12: per-block aggregates
#define OFF_S   6852        // 131072*12: per-thread scan values (6.3 MB)

__device__ inline void mm12(double* C, const double* A_, const double* B_, int t) {
  if (t < 144) {
    int i = t / 12, j = t % 12;
    double s = 0.0;
#pragma unroll
    for (int k = 0; k < 12; ++k) s += A_[i*12+k] * B_[k*12+j];
    C[t] = s;
  }
  __syncthreads();
}

__global__ void setup_kernel(const float* __restrict__ t_eval,
                             const float* __restrict__ A,
                             const float* __restrict__ Bm,
                             const float* __restrict__ loads_raw,
                             const float* __restrict__ areas,
                             float* __restrict__ ws) {
  __shared__ double H[144], H2[144], H3[144], H4[144];
  __shared__ double Pa[144], Pb[144], R[144];
  __shared__ double bq[12], b0[12];
  int t = threadIdx.x;
  double h = (double)t_eval[1] - (double)t_eval[0];
  if (t < 144) H[t] = h * (double)A[t];
  if (t < 12) {
    b0[t] = (double)Bm[t*11];
    double s = 0.0;
    for (int r = 0; r < 10; ++r) {
      double g = 50.0 / (1.0 + exp(-(double)loads_raw[10 + r]));  // gain row
      s += (double)Bm[t*11 + 1 + r] * (g * (double)areas[r]);
    }
    bq[t] = s;
  }
  __syncthreads();
  mm12(H2, H, H, t);
  mm12(H3, H2, H, t);
  mm12(H4, H2, H2, t);
  // c=(h/6)[6I+3H+H^2+H^3/4]Bq ; al=(h/6)[3I+2H+.75H^2+.25H^3]b0 ;
  // be=(h/6)[3I+H+.25H^2]b0
  if (t < 12) {
    double hb=0,h2b=0,h3b=0,hb0=0,h2b0=0,h3b0=0;
    for (int k = 0; k < 12; ++k) {
      hb  += H[t*12+k]*bq[k];  h2b  += H2[t*12+k]*bq[k];  h3b  += H3[t*12+k]*bq[k];
      hb0 += H[t*12+k]*b0[k];  h2b0 += H2[t*12+k]*b0[k];  h3b0 += H3[t*12+k]*b0[k];
    }
    double h6 = h / 6.0;
    ws[OFF_C  + t] = (float)(h6*(6.0*bq[t] + 3.0*hb + h2b + 0.25*h3b));
    ws[OFF_AL + t] = (float)(h6*(3.0*b0[t] + 2.0*hb0 + 0.75*h2b0 + 0.25*h3b0));
    ws[OFF_BE + t] = (float)(h6*(3.0*b0[t] + hb0 + 0.25*h2b0));
  }
  if (t < 144) {
    int i = t/12, j = t%12;
    double m = (i==j ? 1.0 : 0.0) + H[t] + 0.5*H2[t] + H3[t]/6.0 + H4[t]/24.0;
    Pa[t] = m;
    ws[OFF_M + t] = (float)m;
  }
  __syncthreads();
  // squarings: after iter i, src = M^(2^i). P2[l]=M^(8*2^l) at i=l+3 (l=0..8);
  // M^4096 at i=12 -> keep in R, also Pd[1].
  double* src = Pa; double* dst = Pb;
  for (int i = 1; i <= 12; ++i) {
    mm12(dst, src, src, t);
    double* tmp = src; src = dst; dst = tmp;
    if (i >= 3 && i <= 11 && t < 144) ws[OFF_P2 + (i-3)*144 + t] = (float)src[t];
    if (i == 12 && t < 144) { R[t] = src[t]; ws[OFF_PD + 144 + t] = (float)src[t]; }
    __syncthreads();
  }
  if (t < 144) ws[OFF_PD + t] = (t % 13 == 0) ? 1.f : 0.f;   // Pd[0] = I
  // Pd[j] = Pd[j-1] * M^4096
  for (int j = 2; j < NLOOK; ++j) {
    mm12(dst, src, R, t);
    double* tmp = src; src = dst; dst = tmp;
    if (t < 144) ws[OFF_PD + j*144 + t] = (float)src[t];
    __syncthreads();
  }
}

__global__ void __launch_bounds__(BLK) fold_scan(
    const float* __restrict__ wsc, const float* __restrict__ To,
    const float* __restrict__ x0, float* __restrict__ ws) {
  __shared__ float lw[BLK][13];                 // stride 13: 2-way max (free)
  __shared__ __align__(16) float Pc[NLVL][144];
  int k = threadIdx.x, b = blockIdx.x;
  for (int idx = k; idx < NLVL*144; idx += BLK)
    Pc[idx/144][idx%144] = wsc[OFF_P2 + idx];
  float Mv[144];
#pragma unroll
  for (int i = 0; i < 36; ++i) {
    float4 q = reinterpret_cast<const float4*>(wsc + OFF_M)[i];
    Mv[4*i+0]=q.x; Mv[4*i+1]=q.y; Mv[4*i+2]=q.z; Mv[4*i+3]=q.w;
  }
  float cv[12], al[12], be[12];
#pragma unroll
  for (int i = 0; i < 12; ++i) { cv[i]=wsc[OFF_C+i]; al[i]=wsc[OFF_AL+i]; be[i]=wsc[OFF_BE+i]; }
  int g = b * BLK + k;
  float x[12];
#pragma unroll
  for (int i = 0; i < 12; ++i) x[i] = 0.f;
  if (g == 0) {
#pragma unroll
    for (int i = 0; i < 12; ++i) x[i] = x0[i];  // fold x0 into chunk 0
  }
  int base = g * CH;
#pragma unroll
  for (int s = 0; s < CH; ++s) {
    int tt = base + s;
    if (tt < S_STEPS) {                         // identity beyond the tail
      float tot = To[tt], ton = To[tt+1];
      float xn[12];
#pragma unroll
      for (int i = 0; i < 12; ++i) {
        float acc = cv[i] + al[i]*tot + be[i]*ton;
#pragma unroll
        for (int m = 0; m < 12; ++m) acc = fmaf(Mv[i*12+m], x[m], acc);
        xn[i] = acc;
      }
#pragma unroll
      for (int i = 0; i < 12; ++i) x[i] = xn[i];
    }
  }
#pragma unroll
  for (int i = 0; i < 12; ++i) lw[k][i] = x[i];
  __syncthreads();                              // also covers Pc staging
  for (int l = 0; l < NLVL; ++l) {
    int off = 1 << l;
    float nb[12];
    if (k >= off) {
#pragma unroll
      for (int i = 0; i < 12; ++i) nb[i] = lw[k-off][i];
    }
    __syncthreads();
    if (k >= off) {
#pragma unroll
      for (int i = 0; i < 12; ++i) {
        const float4* Pr = reinterpret_cast<const float4*>(&Pc[l][i*12]);
        float4 q0 = Pr[0], q1 = Pr[1], q2 = Pr[2];
        float acc = x[i];
        acc = fmaf(q0.x, nb[0], acc); acc = fmaf(q0.y, nb[1], acc);
        acc = fmaf(q0.z, nb[2], acc); acc = fmaf(q0.w, nb[3], acc);
        acc = fmaf(q1.x, nb[4], acc); acc = fmaf(q1.y, nb[5], acc);
        acc = fmaf(q1.z, nb[6], acc); acc = fmaf(q1.w, nb[7], acc);
        acc = fmaf(q2.x, nb[8], acc); acc = fmaf(q2.y, nb[9], acc);
        acc = fmaf(q2.z, nb[10], acc); acc = fmaf(q2.w, nb[11], acc);
        x[i] = acc;
      }
#pragma unroll
      for (int i = 0; i < 12; ++i) lw[k][i] = x[i];
    }
    __syncthreads();
  }
#pragma unroll
  for (int i = 0; i < 12; ++i) ws[OFF_S + (size_t)g*12 + i] = x[i];
  if (k == BLK-1) {
#pragma unroll
    for (int i = 0; i < 12; ++i) ws[OFF_AGG + b*12 + i] = x[i];
  }
}

__global__ void __launch_bounds__(BLK) fixup_expand(
    const float* __restrict__ ws, const float* __restrict__ To,
    const float* __restrict__ x0, float* __restrict__ out) {
  __shared__ __align__(16) float P2s[NLVL][144];
  __shared__ float part[NLOOK][12];
  __shared__ float Xs[12];
  int k = threadIdx.x, b = blockIdx.x;
  for (int idx = k; idx < NLVL*144; idx += BLK)
    P2s[idx/144][idx%144] = ws[OFF_P2 + idx];
  // truncated lookback: Xstart_b = sum_{d=1..16} M^(4096(d-1)) * agg[b-d]
  if (k < NLOOK*12) {
    int j = k / 12, i = k % 12, src = b - 1 - j;
    float acc = 0.f;
    if (src >= 0) {
#pragma unroll
      for (int m = 0; m < 12; ++m)
        acc = fmaf(ws[OFF_PD + j*144 + i*12 + m], ws[OFF_AGG + src*12 + m], acc);
    }
    part[j][i] = acc;
  }
  __syncthreads();
  if (k < 12) {
    float s = 0.f;
#pragma unroll
    for (int j = 0; j < NLOOK; ++j) s += part[j][k];
    Xs[k] = s;
  }
  __syncthreads();
  // per-thread prefix: v = M^(8k) * Xstart via bit decomposition of k
  float v[12];
#pragma unroll
  for (int i = 0; i < 12; ++i) v[i] = Xs[i];
  for (int l = 0; l < NLVL; ++l) {
    if ((k >> l) & 1) {
      float vn[12];
#pragma unroll
      for (int i = 0; i < 12; ++i) {
        const float4* Pr = reinterpret_cast<const float4*>(&P2s[l][i*12]);
        float4 q0 = Pr[0], q1 = Pr[1], q2 = Pr[2];
        float acc = 0.f;
        acc = fmaf(q0.x, v[0], acc); acc = fmaf(q0.y, v[1], acc);
        acc = fmaf(q0.z, v[2], acc); acc = fmaf(q0.w, v[3], acc);
        acc = fmaf(q1.x, v[4], acc); acc = fmaf(q1.y, v[5], acc);
        acc = fmaf(q1.z, v[6], acc); acc = fmaf(q1.w, v[7], acc);
        acc = fmaf(q2.x, v[8], acc); acc = fmaf(q2.y, v[9], acc);
        acc = fmaf(q2.z, v[10], acc); acc = fmaf(q2.w, v[11], acc);
        vn[i] = acc;
      }
#pragma unroll
      for (int i = 0; i < 12; ++i) v[i] = vn[i];
    }
  }
  int g = b * BLK + k;
  float x[12];
  if (k > 0) {
#pragma unroll
    for (int i = 0; i < 12; ++i) x[i] = v[i] + ws[OFF_S + (size_t)(g-1)*12 + i];
  } else {
#pragma unroll
    for (int i = 0; i < 12; ++i) x[i] = v[i] + (b == 0 ? x0[i] : 0.f);
  }
  float Mv[144];
#pragma unroll
  for (int i = 0; i < 36; ++i) {
    float4 q = reinterpret_cast<const float4*>(ws + OFF_M)[i];
    Mv[4*i+0]=q.x; Mv[4*i+1]=q.y; Mv[4*i+2]=q.z; Mv[4*i+3]=q.w;
  }
  float cv[12], al[12], be[12];
#pragma unroll
  for (int i = 0; i < 12; ++i) { cv[i]=ws[OFF_C+i]; al[i]=ws[OFF_AL+i]; be[i]=ws[OFF_BE+i]; }
  if (b == 0 && k == 0) {
#pragma unroll
    for (int i = 0; i < 12; ++i) out[i] = x0[i];   // row 0
  }
  int base = g * CH;
#pragma unroll
  for (int s = 0; s < CH; ++s) {
    int tt = base + s;
    if (tt >= S_STEPS) break;
    float tot = To[tt], ton = To[tt+1];
    float xn[12];
#pragma unroll
    for (int i = 0; i < 12; ++i) {
      float acc = cv[i] + al[i]*tot + be[i]*ton;
#pragma unroll
      for (int m = 0; m < 12; ++m) acc = fmaf(Mv[i*12+m], x[m], acc);
      xn[i] = acc;
    }
    float4* op = reinterpret_cast<float4*>(out + (size_t)(tt+1)*12);
    op[0] = make_float4(xn[0],xn[1],xn[2],xn[3]);
    op[1] = make_float4(xn[4],xn[5],xn[6],xn[7]);
    op[2] = make_float4(xn[8],xn[9],xn[10],xn[11]);
#pragma unroll
    for (int i = 0; i < 12; ++i) x[i] = xn[i];
  }
}

extern "C" void kernel_launch(void* const* d_in, const int* in_sizes, int n_in,
                              void* d_out, int out_size, void* d_ws, size_t ws_size,
                              hipStream_t stream) {
  const float* t_eval    = (const float*)d_in[0];
  const float* x0        = (const float*)d_in[1];
  const float* A         = (const float*)d_in[2];
  const float* B         = (const float*)d_in[3];
  const float* To        = (const float*)d_in[4];
  const float* loads_raw = (const float*)d_in[5];
  const float* areas     = (const float*)d_in[6];
  float* out = (float*)d_out;
  float* ws  = (float*)d_ws;

  setup_kernel<<<1, 256, 0, stream>>>(t_eval, A, B, loads_raw, areas, ws);
  fold_scan<<<NB, BLK, 0, stream>>>(ws, To, x0, ws);
  fixup_expand<<<NB, BLK, 0, stream>>>(ws, To, x0, out);
}

// Round 3
// 140.280 us; speedup vs baseline: 1.3330x; 1.3330x over previous
//
#include <hip/hip_runtime.h>
#include <math.h>

// RC thermal model: x' = A x + b0*To(t) + Bq, RK4 h=30, T=1e6 steps.
// Per step: x_{t+1} = M x_t + c + al*To[t] + be*To[t+1].
// R3 design rule: NO large per-thread arrays (R2 showed the compiler demotes
// a 144-float M to per-use memory loads: VGPR_Count=40, 88us). All matrices
// live in LDS, read per use as broadcast float4 (uniform addr = conflict-free).
// Fold collapse: chunk aggregate is linear in the To window:
//   v = K[:,0] + sum_{s=0..8} K[:,s+1]*To[t0+s],  K precomputed fp64 (120 FMA).

#define S_STEPS 999999
#define CH      8
#define BLK     512
#define NB      256          // 256*512 threads, 1 chunk each = 1,048,576 steps
#define NLVL    9
#define NLOOK   16           // M^(4096*16) ~ 3e-9: truncated cross-block prefix
#define NCHUNK  125000       // active chunks (last one partial: 7 steps)
#define LASTFULL 124998      // g <= LASTFULL: To[8g+8] in bounds (full window)

// ws float offsets (constants block 0..1608 staged to LDS as one piece)
#define OFF_MX  0            // 12*16: rows [M[i][0..11], c_i, al_i, be_i, 0]
#define OFF_K   192          // 10*12 col-major (col 0 = const col)
#define OFF_P2  312          // 9*144: P2[l] = M^(8*2^l)
#define NCONS   1608
#define OFF_PD  1608         // 16*144: Pd[j] = M^(4096*j), Pd[0]=I
#define OFF_AGG 3912         // 256*12 block aggregates
#define OFF_S   6984         // 131072*12 per-chunk scan values (~6.3 MB)

__device__ inline void mm12(double* C, const double* A_, const double* B_, int t) {
  if (t < 144) {
    int i = t / 12, j = t % 12;
    double s = 0.0;
#pragma unroll
    for (int k = 0; k < 12; ++k) s += A_[i*12+k] * B_[k*12+j];
    C[t] = s;
  }
  __syncthreads();
}

// out += P(12x12, LDS broadcast) * in
__device__ inline void matvec12_acc(const float* __restrict__ P,
                                    const float* in, float* out) {
#pragma unroll
  for (int i = 0; i < 12; ++i) {
    const float4* Pr = reinterpret_cast<const float4*>(P + i*12);
    float4 q0 = Pr[0], q1 = Pr[1], q2 = Pr[2];
    float acc = out[i];
    acc=fmaf(q0.x,in[0],acc); acc=fmaf(q0.y,in[1],acc); acc=fmaf(q0.z,in[2],acc); acc=fmaf(q0.w,in[3],acc);
    acc=fmaf(q1.x,in[4],acc); acc=fmaf(q1.y,in[5],acc); acc=fmaf(q1.z,in[6],acc); acc=fmaf(q1.w,in[7],acc);
    acc=fmaf(q2.x,in[8],acc); acc=fmaf(q2.y,in[9],acc); acc=fmaf(q2.z,in[10],acc); acc=fmaf(q2.w,in[11],acc);
    out[i] = acc;
  }
}

__global__ void setup_kernel(const float* __restrict__ t_eval,
                             const float* __restrict__ A,
                             const float* __restrict__ Bm,
                             const float* __restrict__ loads_raw,
                             const float* __restrict__ areas,
                             float* __restrict__ ws) {
  __shared__ double Md[144], T2[144], CUR[144], R4[144];
  __shared__ double H1[144], H2[144], H3[144], H4[144];
  __shared__ double cd[12], ald[12], bed[12], bqd[12], b0d[12];
  __shared__ double Kd[120];      // [col][row], col0 = const
  int t = threadIdx.x;            // 256 threads
  double h = (double)t_eval[1] - (double)t_eval[0];
  if (t < 144) H1[t] = h * (double)A[t];
  if (t < 12) {
    b0d[t] = (double)Bm[t*11];
    double s = 0.0;
    for (int r = 0; r < 10; ++r) {
      double g = 50.0 / (1.0 + exp(-(double)loads_raw[10 + r]));
      s += (double)Bm[t*11 + 1 + r] * (g * (double)areas[r]);
    }
    bqd[t] = s;
  }
  if (t < 120) Kd[t] = 0.0;
  __syncthreads();
  mm12(H2, H1, H1, t);
  mm12(H3, H2, H1, t);
  mm12(H4, H2, H2, t);
  // c=(h/6)(6I+3H+H^2+H^3/4)Bq ; al=(h/6)(3I+2H+.75H^2+.25H^3)b0 ;
  // be=(h/6)(3I+H+.25H^2)b0
  if (t < 12) {
    double hb=0,h2b=0,h3b=0,hb0=0,h2b0=0,h3b0=0;
    for (int k = 0; k < 12; ++k) {
      hb  += H1[t*12+k]*bqd[k]; h2b  += H2[t*12+k]*bqd[k]; h3b  += H3[t*12+k]*bqd[k];
      hb0 += H1[t*12+k]*b0d[k]; h2b0 += H2[t*12+k]*b0d[k]; h3b0 += H3[t*12+k]*b0d[k];
    }
    double h6 = h / 6.0;
    cd[t]  = h6*(6.0*bqd[t] + 3.0*hb + h2b + 0.25*h3b);
    ald[t] = h6*(3.0*b0d[t] + 2.0*hb0 + 0.75*h2b0 + 0.25*h3b0);
    bed[t] = h6*(3.0*b0d[t] + hb0 + 0.25*h2b0);
  }
  if (t < 144) {
    int i = t/12, j = t%12;
    Md[t] = (i==j ? 1.0 : 0.0) + H1[t] + 0.5*H2[t] + H3[t]/6.0 + H4[t]/24.0;
  }
  if (t < 144) CUR[t] = (t % 13 == 0) ? 1.0 : 0.0;   // I
  __syncthreads();
  // Mx rows: [M | c al be 0]
  if (t < 192) {
    int i = t/16, j = t%16;
    float val = (j < 12) ? (float)Md[i*12+j]
              : (j == 12) ? (float)cd[i]
              : (j == 13) ? (float)ald[i]
              : (j == 14) ? (float)bed[i] : 0.f;
    ws[OFF_MX + t] = val;
  }
  // K accumulation: at iter k, CUR = M^k.
  // To[t0+u] coeff: M^(7-u) al (u<=7)  +  M^(8-u) be (u>=1); const: sum M^k c.
  for (int k = 0; k <= 8; ++k) {
    if (k > 0) {
      mm12(T2, CUR, Md, t);
      if (t < 144) CUR[t] = T2[t];
      __syncthreads();
    }
    if (t < 12 && k <= 7) {
      double sa=0, sb=0, sc=0;
      for (int j = 0; j < 12; ++j) {
        double m = CUR[t*12+j];
        sa += m*ald[j]; sb += m*bed[j]; sc += m*cd[j];
      }
      Kd[(8-k)*12 + t] += sa;   // col 1+u, u=7-k
      Kd[(9-k)*12 + t] += sb;   // col 1+u, u=8-k
      Kd[t]            += sc;   // const col
    }
    __syncthreads();
  }
  if (t < 120) ws[OFF_K + t] = (float)Kd[t];
  if (t < 144) ws[OFF_P2 + t] = (float)CUR[t];        // M^8
  // squarings: P2[l] = M^(8*2^l)
  for (int l = 1; l <= 8; ++l) {
    mm12(T2, CUR, CUR, t);
    if (t < 144) CUR[t] = T2[t];
    __syncthreads();
    if (t < 144) ws[OFF_P2 + l*144 + t] = (float)CUR[t];
  }
  mm12(R4, CUR, CUR, t);                               // M^4096
  if (t < 144) {
    ws[OFF_PD + t] = (t % 13 == 0) ? 1.f : 0.f;        // Pd[0]=I
    ws[OFF_PD + 144 + t] = (float)R4[t];
    CUR[t] = R4[t];
  }
  __syncthreads();
  for (int j = 2; j < NLOOK; ++j) {
    mm12(T2, CUR, R4, t);
    if (t < 144) CUR[t] = T2[t];
    __syncthreads();
    if (t < 144) ws[OFF_PD + j*144 + t] = (float)CUR[t];
  }
}

__global__ void __launch_bounds__(BLK) fold_scan(
    float* __restrict__ ws, const float* __restrict__ To,
    const float* __restrict__ x0) {
  __shared__ __align__(16) float cons[NCONS];
  __shared__ float lw[BLK*13];              // stride 13: conflict-free scalar
  int k = threadIdx.x, b = blockIdx.x;
  int g = b*BLK + k;
  for (int idx = k; idx < NCONS; idx += BLK) cons[idx] = ws[idx];
  const float* Ks  = cons + OFF_K;
  const float* P2s = cons + OFF_P2;
  // To window (before barrier; independent of LDS)
  float to[9];
  int base = g*CH;
  bool fullc = (g <= LASTFULL);
  if (fullc) {
    const float4* tp = reinterpret_cast<const float4*>(To + base);  // 32B-aligned
    float4 a = tp[0], c = tp[1];
    to[0]=a.x; to[1]=a.y; to[2]=a.z; to[3]=a.w;
    to[4]=c.x; to[5]=c.y; to[6]=c.z; to[7]=c.w;
    to[8]=To[base+8];
  }
  __syncthreads();
  float v[12];
  if (fullc) {
    const float4* K0 = reinterpret_cast<const float4*>(Ks);
    float4 c0=K0[0], c1=K0[1], c2=K0[2];
    v[0]=c0.x; v[1]=c0.y; v[2]=c0.z; v[3]=c0.w;
    v[4]=c1.x; v[5]=c1.y; v[6]=c1.z; v[7]=c1.w;
    v[8]=c2.x; v[9]=c2.y; v[10]=c2.z; v[11]=c2.w;
#pragma unroll
    for (int s = 0; s < 9; ++s) {
      float ts = to[s];
      const float4* Kp = reinterpret_cast<const float4*>(Ks + (s+1)*12);
      float4 q0=Kp[0], q1=Kp[1], q2=Kp[2];
      v[0]=fmaf(q0.x,ts,v[0]); v[1]=fmaf(q0.y,ts,v[1]); v[2]=fmaf(q0.z,ts,v[2]); v[3]=fmaf(q0.w,ts,v[3]);
      v[4]=fmaf(q1.x,ts,v[4]); v[5]=fmaf(q1.y,ts,v[5]); v[6]=fmaf(q1.z,ts,v[6]); v[7]=fmaf(q1.w,ts,v[7]);
      v[8]=fmaf(q2.x,ts,v[8]); v[9]=fmaf(q2.y,ts,v[9]); v[10]=fmaf(q2.z,ts,v[10]); v[11]=fmaf(q2.w,ts,v[11]);
    }
  } else {
#pragma unroll
    for (int i = 0; i < 12; ++i) v[i] = 0.f;   // partial/pad chunks: value unused
  }
  if (g == 0) {
    float xi[12];
#pragma unroll
    for (int i = 0; i < 12; ++i) xi[i] = x0[i];
    matvec12_acc(P2s, xi, v);                  // v += M^8 x0
  }
#pragma unroll
  for (int i = 0; i < 12; ++i) lw[k*13+i] = v[i];
  __syncthreads();
  for (int l = 0; l < NLVL; ++l) {
    int off = 1 << l;
    float nb[12];
    if (k >= off) {
#pragma unroll
      for (int i = 0; i < 12; ++i) nb[i] = lw[(k-off)*13 + i];
    }
    __syncthreads();
    if (k >= off) {
      matvec12_acc(P2s + l*144, nb, v);        // v = M^(8*2^l)*nb + v
#pragma unroll
      for (int i = 0; i < 12; ++i) lw[k*13+i] = v[i];
    }
    __syncthreads();
  }
  float4* Sp = reinterpret_cast<float4*>(ws + OFF_S + (size_t)g*12);
  Sp[0] = make_float4(v[0],v[1],v[2],v[3]);
  Sp[1] = make_float4(v[4],v[5],v[6],v[7]);
  Sp[2] = make_float4(v[8],v[9],v[10],v[11]);
  if (k == BLK-1) {
#pragma unroll
    for (int i = 0; i < 12; ++i) ws[OFF_AGG + b*12 + i] = v[i];
  }
}

__global__ void __launch_bounds__(BLK) fixup_expand(
    const float* __restrict__ ws, const float* __restrict__ To,
    const float* __restrict__ x0, float* __restrict__ out) {
  __shared__ __align__(16) float cons[NCONS];
  __shared__ float partl[NLOOK*12];
  __shared__ float Xs[12];
  int k = threadIdx.x, b = blockIdx.x;
  int g = b*BLK + k;
  for (int idx = k; idx < NCONS; idx += BLK) cons[idx] = ws[idx];
  const float* Mxs = cons + OFF_MX;
  const float* P2s = cons + OFF_P2;
  // truncated lookback: Xstart_b = sum_{d=1..16} M^(4096(d-1)) * agg[b-d]
  if (k < NLOOK*12) {
    int j = k/12, i = k%12, src = b - 1 - j;
    float acc = 0.f;
    if (src >= 0) {
#pragma unroll
      for (int m = 0; m < 12; ++m)
        acc = fmaf(ws[OFF_PD + j*144 + i*12 + m], ws[OFF_AGG + src*12 + m], acc);
    }
    partl[k] = acc;
  }
  __syncthreads();
  if (k < 12) {
    float s = 0.f;
#pragma unroll
    for (int j = 0; j < NLOOK; ++j) s += partl[j*12 + k];
    Xs[k] = s;
  }
  __syncthreads();
  // prefix: v = M^(8k) * Xstart via bit decomposition (P2s broadcast)
  float v[12];
#pragma unroll
  for (int i = 0; i < 12; ++i) v[i] = Xs[i];
  for (int l = 0; l < NLVL; ++l) {
    if ((k >> l) & 1) {
      float vn[12];
#pragma unroll
      for (int i = 0; i < 12; ++i) vn[i] = 0.f;
      matvec12_acc(P2s + l*144, v, vn);
#pragma unroll
      for (int i = 0; i < 12; ++i) v[i] = vn[i];
    }
  }
  float x[12];
  if (k > 0) {
    const float4* Sp = reinterpret_cast<const float4*>(ws + OFF_S + (size_t)(g-1)*12);
    float4 s0=Sp[0], s1=Sp[1], s2=Sp[2];
    x[0]=v[0]+s0.x; x[1]=v[1]+s0.y; x[2]=v[2]+s0.z; x[3]=v[3]+s0.w;
    x[4]=v[4]+s1.x; x[5]=v[5]+s1.y; x[6]=v[6]+s1.z; x[7]=v[7]+s1.w;
    x[8]=v[8]+s2.x; x[9]=v[9]+s2.y; x[10]=v[10]+s2.z; x[11]=v[11]+s2.w;
  } else {
#pragma unroll
    for (int i = 0; i < 12; ++i) x[i] = v[i] + (b == 0 ? x0[i] : 0.f);
  }
  if (b == 0 && k == 0) {
#pragma unroll
    for (int i = 0; i < 12; ++i) out[i] = x0[i];       // row 0
  }
  if (g >= NCHUNK) return;
  int base = g*CH;
  float to[9];
  {
    const float4* tp = reinterpret_cast<const float4*>(To + base);
    float4 a = tp[0], c = tp[1];                        // max idx 999999: in bounds
    to[0]=a.x; to[1]=a.y; to[2]=a.z; to[3]=a.w;
    to[4]=c.x; to[5]=c.y; to[6]=c.z; to[7]=c.w;
    to[8] = (g <= LASTFULL) ? To[base+8] : 0.f;
  }
#pragma unroll
  for (int s = 0; s < CH; ++s) {
    int tt = base + s;
    if (tt >= S_STEPS) break;
    float tot = to[s], ton = to[s+1];
    float xn[12];
#pragma unroll
    for (int i = 0; i < 12; ++i) {
      const float4* Mr = reinterpret_cast<const float4*>(Mxs + i*16);
      float4 q0=Mr[0], q1=Mr[1], q2=Mr[2], q3=Mr[3];
      float acc = q3.x;                                 // c_i
      acc = fmaf(q3.y, tot, acc);                       // al_i*To[t]
      acc = fmaf(q3.z, ton, acc);                       // be_i*To[t+1]
      acc=fmaf(q0.x,x[0],acc); acc=fmaf(q0.y,x[1],acc); acc=fmaf(q0.z,x[2],acc); acc=fmaf(q0.w,x[3],acc);
      acc=fmaf(q1.x,x[4],acc); acc=fmaf(q1.y,x[5],acc); acc=fmaf(q1.z,x[6],acc); acc=fmaf(q1.w,x[7],acc);
      acc=fmaf(q2.x,x[8],acc); acc=fmaf(q2.y,x[9],acc); acc=fmaf(q2.z,x[10],acc); acc=fmaf(q2.w,x[11],acc);
      xn[i] = acc;
    }
    float4* op = reinterpret_cast<float4*>(out + (size_t)(tt+1)*12);
    op[0] = make_float4(xn[0],xn[1],xn[2],xn[3]);
    op[1] = make_float4(xn[4],xn[5],xn[6],xn[7]);
    op[2] = make_float4(xn[8],xn[9],xn[10],xn[11]);
#pragma unroll
    for (int i = 0; i < 12; ++i) x[i] = xn[i];
  }
}

extern "C" void kernel_launch(void* const* d_in, const int* in_sizes, int n_in,
                              void* d_out, int out_size, void* d_ws, size_t ws_size,
                              hipStream_t stream) {
  const float* t_eval    = (const float*)d_in[0];
  const float* x0        = (const float*)d_in[1];
  const float* A         = (const float*)d_in[2];
  const float* B         = (const float*)d_in[3];
  const float* To        = (const float*)d_in[4];
  const float* loads_raw = (const float*)d_in[5];
  const float* areas     = (const float*)d_in[6];
  float* out = (float*)d_out;
  float* ws  = (float*)d_ws;

  setup_kernel<<<1, 256, 0, stream>>>(t_eval, A, B, loads_raw, areas, ws);
  fold_scan<<<NB, BLK, 0, stream>>>(ws, To, x0);
  fixup_expand<<<NB, BLK, 0, stream>>>(ws, To, x0, out);
}

// Round 4
// 137.048 us; speedup vs baseline: 1.3645x; 1.0236x over previous
//
#include <hip/hip_runtime.h>
#include <math.h>

// RC thermal model: x' = A x + b0*To(t) + Bq, RK4 h=30, T=1e6 steps.
// Per step: x_{t+1} = M x_t + c + al*To[t] + be*To[t+1].
// R4 design rule: wave-uniform matrices are read from GLOBAL memory at
// thread-independent addresses through const __restrict__ pointers ->
// compiler emits s_load via the scalar K-cache, FMAs take the matrix
// element as an SGPR operand. (R3 put them in LDS: 48 ds_read_b128 per
// step per wave saturated the LDS pipe; R2 put them in a 144-float
// per-thread array: compiler demoted it to per-use loads.)
// Fold collapse: chunk aggregate is linear in the To window:
//   v = K[:,0] + sum_s K[:,s+1]*To[t0+s], K precomputed in fp64.

#define S_STEPS 999999
#define CH      8
#define BLK     512
#define NB      256          // 256*512 threads, 1 chunk each = 1,048,576 steps
#define NLVL    9
#define NLOOK   16           // M^(4096*16) ~ 3e-9: truncated cross-block prefix
#define NCHUNK  125000       // active chunks (last one partial: 7 steps)
#define LASTFULL 124998      // g <= LASTFULL: To[8g+8] in bounds (full window)

// ws float offsets
#define OFF_MX  0            // 12*16 rows: [M[i][0..11], c_i, al_i, be_i, 0]
#define OFF_K   192          // 10*12 col-major (col 0 = const col)
#define OFF_P2  312          // 9*144: P2[l] = M^(8*2^l)
#define OFF_PD  1608         // 16*144: Pd[j] = M^(4096*j), Pd[0]=I
#define OFF_AGG 3912         // 256*12 block aggregates
#define OFF_S   6984         // 131072*12 per-chunk scan values (~6.3 MB)

__device__ inline void mm12(double* C, const double* A_, const double* B_, int t) {
  if (t < 144) {
    int i = t / 12, j = t % 12;
    double s = 0.0;
#pragma unroll
    for (int k = 0; k < 12; ++k) s += A_[i*12+k] * B_[k*12+j];
    C[t] = s;
  }
  __syncthreads();
}

// out += P * in, P at a wave-uniform global address (-> s_load / SGPR)
__device__ inline void matvec12_s(const float* __restrict__ P,
                                  const float* in, float* out) {
#pragma unroll
  for (int i = 0; i < 12; ++i) {
    float acc = out[i];
#pragma unroll
    for (int j = 0; j < 12; ++j) acc = fmaf(P[i*12+j], in[j], acc);
    out[i] = acc;
  }
}

__global__ void setup_kernel(const float* __restrict__ t_eval,
                             const float* __restrict__ A,
                             const float* __restrict__ Bm,
                             const float* __restrict__ loads_raw,
                             const float* __restrict__ areas,
                             float* __restrict__ ws) {
  __shared__ double Md[144], T2[144], CUR[144], R4[144];
  __shared__ double H1[144], H2[144], H3[144], H4[144];
  __shared__ double cd[12], ald[12], bed[12], bqd[12], b0d[12];
  __shared__ double Kd[120];      // [col][row], col0 = const
  int t = threadIdx.x;            // 256 threads
  double h = (double)t_eval[1] - (double)t_eval[0];
  if (t < 144) H1[t] = h * (double)A[t];
  if (t < 12) {
    b0d[t] = (double)Bm[t*11];
    double s = 0.0;
    for (int r = 0; r < 10; ++r) {
      double g = 50.0 / (1.0 + exp(-(double)loads_raw[10 + r]));
      s += (double)Bm[t*11 + 1 + r] * (g * (double)areas[r]);
    }
    bqd[t] = s;
  }
  if (t < 120) Kd[t] = 0.0;
  __syncthreads();
  mm12(H2, H1, H1, t);
  mm12(H3, H2, H1, t);
  mm12(H4, H2, H2, t);
  if (t < 12) {
    double hb=0,h2b=0,h3b=0,hb0=0,h2b0=0,h3b0=0;
    for (int k = 0; k < 12; ++k) {
      hb  += H1[t*12+k]*bqd[k]; h2b  += H2[t*12+k]*bqd[k]; h3b  += H3[t*12+k]*bqd[k];
      hb0 += H1[t*12+k]*b0d[k]; h2b0 += H2[t*12+k]*b0d[k]; h3b0 += H3[t*12+k]*b0d[k];
    }
    double h6 = h / 6.0;
    cd[t]  = h6*(6.0*bqd[t] + 3.0*hb + h2b + 0.25*h3b);
    ald[t] = h6*(3.0*b0d[t] + 2.0*hb0 + 0.75*h2b0 + 0.25*h3b0);
    bed[t] = h6*(3.0*b0d[t] + hb0 + 0.25*h2b0);
  }
  if (t < 144) {
    int i = t/12, j = t%12;
    Md[t] = (i==j ? 1.0 : 0.0) + H1[t] + 0.5*H2[t] + H3[t]/6.0 + H4[t]/24.0;
  }
  if (t < 144) CUR[t] = (t % 13 == 0) ? 1.0 : 0.0;   // I
  __syncthreads();
  if (t < 192) {
    int i = t/16, j = t%16;
    float val = (j < 12) ? (float)Md[i*12+j]
              : (j == 12) ? (float)cd[i]
              : (j == 13) ? (float)ald[i]
              : (j == 14) ? (float)bed[i] : 0.f;
    ws[OFF_MX + t] = val;
  }
  // K: at iter k, CUR = M^k. To[t0+u] coeff: M^(7-u) al (u<=7) + M^(8-u) be
  // (u>=1); const col: sum M^k c.
  for (int k = 0; k <= 8; ++k) {
    if (k > 0) {
      mm12(T2, CUR, Md, t);
      if (t < 144) CUR[t] = T2[t];
      __syncthreads();
    }
    if (t < 12 && k <= 7) {
      double sa=0, sb=0, sc=0;
      for (int j = 0; j < 12; ++j) {
        double m = CUR[t*12+j];
        sa += m*ald[j]; sb += m*bed[j]; sc += m*cd[j];
      }
      Kd[(8-k)*12 + t] += sa;
      Kd[(9-k)*12 + t] += sb;
      Kd[t]            += sc;
    }
    __syncthreads();
  }
  if (t < 120) ws[OFF_K + t] = (float)Kd[t];
  if (t < 144) ws[OFF_P2 + t] = (float)CUR[t];        // M^8
  for (int l = 1; l <= 8; ++l) {
    mm12(T2, CUR, CUR, t);
    if (t < 144) CUR[t] = T2[t];
    __syncthreads();
    if (t < 144) ws[OFF_P2 + l*144 + t] = (float)CUR[t];
  }
  mm12(R4, CUR, CUR, t);                               // M^4096
  if (t < 144) {
    ws[OFF_PD + t] = (t % 13 == 0) ? 1.f : 0.f;        // Pd[0]=I
    ws[OFF_PD + 144 + t] = (float)R4[t];
    CUR[t] = R4[t];
  }
  __syncthreads();
  for (int j = 2; j < NLOOK; ++j) {
    mm12(T2, CUR, R4, t);
    if (t < 144) CUR[t] = T2[t];
    __syncthreads();
    if (t < 144) ws[OFF_PD + j*144 + t] = (float)CUR[t];
  }
}

__global__ void __launch_bounds__(BLK) fold_scan(
    const float* __restrict__ cons, const float* __restrict__ To,
    const float* __restrict__ x0, float* __restrict__ sout,
    float* __restrict__ agg) {
  __shared__ float lw[BLK*13];              // stride 13: conflict-free scalar
  int k = threadIdx.x, b = blockIdx.x;
  int g = b*BLK + k;
  int base = g*CH;
  bool fullc = (g <= LASTFULL);
  float to[9];
  if (fullc) {
    const float4* tp = reinterpret_cast<const float4*>(To + base);  // 32B-aligned
    float4 a = tp[0], c = tp[1];
    to[0]=a.x; to[1]=a.y; to[2]=a.z; to[3]=a.w;
    to[4]=c.x; to[5]=c.y; to[6]=c.z; to[7]=c.w;
    to[8]=To[base+8];
  }
  float v[12];
  if (fullc) {
#pragma unroll
    for (int i = 0; i < 12; ++i) v[i] = cons[OFF_K + i];   // const col (SGPR)
#pragma unroll
    for (int s = 0; s < 9; ++s) {
      float ts = to[s];
#pragma unroll
      for (int i = 0; i < 12; ++i)
        v[i] = fmaf(cons[OFF_K + (s+1)*12 + i], ts, v[i]); // K col (SGPR)
    }
  } else {
#pragma unroll
    for (int i = 0; i < 12; ++i) v[i] = 0.f;   // pad chunks: value unused
  }
  if (g == 0) {
    float xi[12];
#pragma unroll
    for (int i = 0; i < 12; ++i) xi[i] = x0[i];
    matvec12_s(cons + OFF_P2, xi, v);          // v += M^8 x0
  }
#pragma unroll
  for (int i = 0; i < 12; ++i) lw[k*13+i] = v[i];
  __syncthreads();
#pragma unroll
  for (int l = 0; l < NLVL; ++l) {
    int off = 1 << l;
    float nb[12];
    bool act = (k >= off);
    if (act) {
#pragma unroll
      for (int i = 0; i < 12; ++i) nb[i] = lw[(k-off)*13 + i];
    }
    __syncthreads();
    if (act) {
      matvec12_s(cons + OFF_P2 + l*144, nb, v);   // matrix via SGPRs
#pragma unroll
      for (int i = 0; i < 12; ++i) lw[k*13+i] = v[i];
    }
    __syncthreads();
  }
  float4* Sp = reinterpret_cast<float4*>(sout + (size_t)g*12);
  Sp[0] = make_float4(v[0],v[1],v[2],v[3]);
  Sp[1] = make_float4(v[4],v[5],v[6],v[7]);
  Sp[2] = make_float4(v[8],v[9],v[10],v[11]);
  if (k == BLK-1) {
#pragma unroll
    for (int i = 0; i < 12; ++i) agg[b*12 + i] = v[i];
  }
}

__global__ void __launch_bounds__(BLK) fixup_expand(
    const float* __restrict__ ws, const float* __restrict__ To,
    const float* __restrict__ x0, float* __restrict__ out) {
  __shared__ float partl[NLOOK*12];
  __shared__ float Xs[12];
  int k = threadIdx.x, b = blockIdx.x;
  int g = b*BLK + k;
  // truncated lookback: Xstart_b = sum_{d=1..16} M^(4096(d-1)) * agg[b-d]
  if (k < NLOOK*12) {
    int j = k/12, i = k%12, src = b - 1 - j;
    float acc = 0.f;
    if (src >= 0) {
#pragma unroll
      for (int m = 0; m < 12; ++m)
        acc = fmaf(ws[OFF_PD + j*144 + i*12 + m], ws[OFF_AGG + src*12 + m], acc);
    }
    partl[k] = acc;
  }
  __syncthreads();
  if (k < 12) {
    float s = 0.f;
#pragma unroll
    for (int j = 0; j < NLOOK; ++j) s += partl[j*12 + k];
    Xs[k] = s;
  }
  __syncthreads();
  // prefix: v = M^(8k) * Xstart via bit decomposition (P2 via SGPRs)
  float v[12];
#pragma unroll
  for (int i = 0; i < 12; ++i) v[i] = Xs[i];
#pragma unroll
  for (int l = 0; l < NLVL; ++l) {
    if ((k >> l) & 1) {
      float vn[12];
#pragma unroll
      for (int i = 0; i < 12; ++i) vn[i] = 0.f;
      matvec12_s(ws + OFF_P2 + l*144, v, vn);
#pragma unroll
      for (int i = 0; i < 12; ++i) v[i] = vn[i];
    }
  }
  float x[12];
  if (k > 0) {
    const float4* Sp = reinterpret_cast<const float4*>(ws + OFF_S + (size_t)(g-1)*12);
    float4 s0=Sp[0], s1=Sp[1], s2=Sp[2];
    x[0]=v[0]+s0.x; x[1]=v[1]+s0.y; x[2]=v[2]+s0.z; x[3]=v[3]+s0.w;
    x[4]=v[4]+s1.x; x[5]=v[5]+s1.y; x[6]=v[6]+s1.z; x[7]=v[7]+s1.w;
    x[8]=v[8]+s2.x; x[9]=v[9]+s2.y; x[10]=v[10]+s2.z; x[11]=v[11]+s2.w;
  } else {
#pragma unroll
    for (int i = 0; i < 12; ++i) x[i] = v[i] + (b == 0 ? x0[i] : 0.f);
  }
  if (b == 0 && k == 0) {
#pragma unroll
    for (int i = 0; i < 12; ++i) out[i] = x0[i];       // row 0
  }
  if (g >= NCHUNK) return;
  int base = g*CH;
  float to[9];
  {
    const float4* tp = reinterpret_cast<const float4*>(To + base);
    float4 a = tp[0], c = tp[1];                        // max idx 999999: in bounds
    to[0]=a.x; to[1]=a.y; to[2]=a.z; to[3]=a.w;
    to[4]=c.x; to[5]=c.y; to[6]=c.z; to[7]=c.w;
    to[8] = (g <= LASTFULL) ? To[base+8] : 0.f;
  }
#pragma unroll
  for (int s = 0; s < CH; ++s) {
    int tt = base + s;
    if (tt >= S_STEPS) break;
    float tot = to[s], ton = to[s+1];
    float xn[12];
#pragma unroll
    for (int i = 0; i < 12; ++i) {
      const float* Mr = ws + OFF_MX + i*16;             // uniform -> SGPRs
      float acc = Mr[12];                               // c_i
      acc = fmaf(Mr[13], tot, acc);
      acc = fmaf(Mr[14], ton, acc);
#pragma unroll
      for (int m = 0; m < 12; ++m) acc = fmaf(Mr[m], x[m], acc);
      xn[i] = acc;
    }
    float4* op = reinterpret_cast<float4*>(out + (size_t)(tt+1)*12);
    op[0] = make_float4(xn[0],xn[1],xn[2],xn[3]);
    op[1] = make_float4(xn[4],xn[5],xn[6],xn[7]);
    op[2] = make_float4(xn[8],xn[9],xn[10],xn[11]);
#pragma unroll
    for (int i = 0; i < 12; ++i) x[i] = xn[i];
  }
}

extern "C" void kernel_launch(void* const* d_in, const int* in_sizes, int n_in,
                              void* d_out, int out_size, void* d_ws, size_t ws_size,
                              hipStream_t stream) {
  const float* t_eval    = (const float*)d_in[0];
  const float* x0        = (const float*)d_in[1];
  const float* A         = (const float*)d_in[2];
  const float* B         = (const float*)d_in[3];
  const float* To        = (const float*)d_in[4];
  const float* loads_raw = (const float*)d_in[5];
  const float* areas     = (const float*)d_in[6];
  float* out = (float*)d_out;
  float* ws  = (float*)d_ws;

  setup_kernel<<<1, 256, 0, stream>>>(t_eval, A, B, loads_raw, areas, ws);
  fold_scan<<<NB, BLK, 0, stream>>>(ws, To, x0, ws + OFF_S, ws + OFF_AGG);
  fixup_expand<<<NB, BLK, 0, stream>>>(ws, To, x0, out);
}

// Round 6
// 135.562 us; speedup vs baseline: 1.3794x; 1.0110x over previous
//
#include <hip/hip_runtime.h>
#include <math.h>

// RC thermal model: x' = A x + b0*To(t) + Bq, RK4 h=30, T=1e6 steps.
// Per step: x_{t+1} = M x_t + c + al*To[t] + be*To[t+1].
// R6: K1 computes per-block (4096-step) aggregates only (wave-shfl
// REDUCTION -- aligned segments, no seam bug -- + 3-level LDS tree).
// K2 fuses fold + proven 9-level LDS Hillis-Steele scan + truncated
// 16-block lookback + hierarchical prefix M^(8k)Xs + 8-step expand.
// R5's bug: shfl wave-SCAN followed by LDS levels drops (k-64, 64w) spans
// for mid-wave lanes. Scans must be pure LDS Hillis-Steele (or prefix-apply).

#define S_STEPS 999999
#define CH      8
#define BLK     512
#define NB      256          // 256*512 chunks = 1,048,576 steps
#define NLOOK   16           // M^(4096*16) ~ 3e-9: truncated lookback
#define NCHUNK  125000       // active chunks (last partial: 7 steps)
#define LASTFULL 124998      // g <= LASTFULL: To[8g+8] in bounds

// ws float offsets (16B-aligned)
#define OFF_M   0            // 144: M
#define OFF_C   144          // 12
#define OFF_AL  156          // 12
#define OFF_BE  168          // 12
#define OFF_K   192          // 120: K cols [col][12], col0 = const
#define OFF_P2  312          // 9*144: P2[l] = M^(8*2^l), l=0..8
#define OFF_PQ  1608         // 3*144: M^(128d), d=1..3
#define OFF_PW  2040         // 7*144: M^(512w), w=1..7
#define OFF_PD  3048         // 16*144: M^(4096j), j=0..15 (Pd[0]=I)
#define OFF_AGG 5352         // 256*12 block aggregates (end 8424)

#define FMA4(Q,a,b,c,d,acc) fmaf((Q).w,(d),fmaf((Q).z,(c),fmaf((Q).y,(b),fmaf((Q).x,(a),(acc)))))

// y += P(12x12 row-major) * x  -- b128 loads
__device__ __forceinline__ void mv_acc(const float* Pf, const float* x, float* y) {
  const float4* P = reinterpret_cast<const float4*>(Pf);
#pragma unroll
  for (int i = 0; i < 12; ++i) {
    float4 a = P[3*i], b = P[3*i+1], c = P[3*i+2];
    y[i] = FMA4(c, x[8],x[9],x[10],x[11],
            FMA4(b, x[4],x[5],x[6],x[7],
             FMA4(a, x[0],x[1],x[2],x[3], y[i])));
  }
}

// v = K[:,0] + sum_{s=0..8} K[:,s+1]*tos[s]
__device__ __forceinline__ void fold_chunk(const float* cons, const float* tos, float* v) {
  const float4* Kq = reinterpret_cast<const float4*>(cons + OFF_K);
  float4 c0=Kq[0], c1=Kq[1], c2=Kq[2];
  v[0]=c0.x; v[1]=c0.y; v[2]=c0.z; v[3]=c0.w;
  v[4]=c1.x; v[5]=c1.y; v[6]=c1.z; v[7]=c1.w;
  v[8]=c2.x; v[9]=c2.y; v[10]=c2.z; v[11]=c2.w;
#pragma unroll
  for (int s = 0; s < 9; ++s) {
    float ts = tos[s];
    float4 ka=Kq[3*(s+1)], kb=Kq[3*(s+1)+1], kc=Kq[3*(s+1)+2];
    v[0]=fmaf(ka.x,ts,v[0]); v[1]=fmaf(ka.y,ts,v[1]); v[2]=fmaf(ka.z,ts,v[2]); v[3]=fmaf(ka.w,ts,v[3]);
    v[4]=fmaf(kb.x,ts,v[4]); v[5]=fmaf(kb.y,ts,v[5]); v[6]=fmaf(kb.z,ts,v[6]); v[7]=fmaf(kb.w,ts,v[7]);
    v[8]=fmaf(kc.x,ts,v[8]); v[9]=fmaf(kc.y,ts,v[9]); v[10]=fmaf(kc.z,ts,v[10]); v[11]=fmaf(kc.w,ts,v[11]);
  }
}

__global__ void __launch_bounds__(512) setup_kernel(
    const float* __restrict__ t_eval, const float* __restrict__ A,
    const float* __restrict__ Bm, const float* __restrict__ loads_raw,
    const float* __restrict__ areas, float* ws) {
  __shared__ double H1[144], H2[144], H3[144], H4[144], Md[144];
  __shared__ double Qa[144], Qb[144], D1536[144];
  __shared__ double C128[144], C256[144], C512[144], C1024[144], C2048[144], C4096[144];
  __shared__ double cd[12], ald[12], bed[12], b0d[12], bqd[12];
  __shared__ double Vv[3][12], Kd[120];
  int t = threadIdx.x;
  double h = (double)t_eval[1] - (double)t_eval[0];
  if (t < 144) H1[t] = h * (double)A[t];
  if (t < 12) {
    b0d[t] = (double)Bm[t*11];
    double s = 0.0;
    for (int r = 0; r < 10; ++r) {
      double gq = 50.0 / (1.0 + exp(-(double)loads_raw[10 + r]));
      s += (double)Bm[t*11 + 1 + r] * (gq * (double)areas[r]);
    }
    bqd[t] = s;
  }
  if (t < 120) Kd[t] = 0.0;
  __syncthreads();
  if (t < 144) {                              // H2 = H1*H1
    int i=t/12, j=t%12; double s=0.0;
#pragma unroll
    for (int m = 0; m < 12; ++m) s += H1[i*12+m]*H1[m*12+j];
    H2[t]=s;
  }
  __syncthreads();
  if (t < 288) {                              // H3 = H2*H1 | H4 = H2*H2
    int w=t/144, e=t%144, i=e/12, j=e%12;
    const double* Bp = w ? H2 : H1;
    double s = 0.0;
#pragma unroll
    for (int m = 0; m < 12; ++m) s += H2[i*12+m]*Bp[m*12+j];
    (w ? H4 : H3)[e] = s;
  }
  __syncthreads();
  // c=(h/6)(6I+3H+H^2+H^3/4)Bq ; al=(h/6)(3I+2H+.75H^2+.25H^3)b0 ;
  // be=(h/6)(3I+H+.25H^2)b0 ; it=0 K contributions; Md = RK4 one-step matrix
  if (t < 12) {
    double hb=0,h2b=0,h3b=0,hb0=0,h2b0=0,h3b0=0;
#pragma unroll
    for (int m = 0; m < 12; ++m) {
      hb  += H1[t*12+m]*bqd[m]; h2b  += H2[t*12+m]*bqd[m]; h3b  += H3[t*12+m]*bqd[m];
      hb0 += H1[t*12+m]*b0d[m]; h2b0 += H2[t*12+m]*b0d[m]; h3b0 += H3[t*12+m]*b0d[m];
    }
    double h6 = h / 6.0;
    cd[t]  = h6*(6.0*bqd[t] + 3.0*hb + h2b + 0.25*h3b);
    ald[t] = h6*(3.0*b0d[t] + 2.0*hb0 + 0.75*h2b0 + 0.25*h3b0);
    bed[t] = h6*(3.0*b0d[t] + hb0 + 0.25*h2b0);
    Vv[0][t]=ald[t]; Vv[1][t]=bed[t]; Vv[2][t]=cd[t];
    Kd[96+t] += ald[t]; Kd[108+t] += bed[t]; Kd[t] += cd[t];
  }
  if (t >= 144 && t < 288) {
    int e=t-144, i=e/12, j=e%12;
    Md[e] = (i==j ? 1.0 : 0.0) + H1[e] + 0.5*H2[e] + H3[e]/6.0 + H4[e]/24.0;
  }
  __syncthreads();
  if (t < 144) { ws[OFF_M+t] = (float)Md[t]; Qa[t] = Md[t]; }
  if (t < 12) {
    ws[OFF_C+t]=(float)cd[t]; ws[OFF_AL+t]=(float)ald[t]; ws[OFF_BE+t]=(float)bed[t];
  }
  __syncthreads();
  // chain r=1..12: src=M^(2^(r-1)) -> dst=M^(2^r); overlapped K iteration
  // (rounds 1..7, threads 256..291): Vv=M^r*{al,be,c}; Kd cols (8-r),(9-r),0
  double* src = Qa; double* dst = Qb;
  for (int r = 1; r <= 12; ++r) {
    double acc = 0.0, ks = 0.0;
    if (t < 144) {
      int i=t/12, j=t%12;
#pragma unroll
      for (int m = 0; m < 12; ++m) acc += src[i*12+m]*src[m*12+j];
    }
    int w=0, i2=0;
    if (r <= 7 && t >= 256 && t < 292) {
      w=(t-256)/12; i2=(t-256)%12;
#pragma unroll
      for (int m = 0; m < 12; ++m) ks += Md[i2*12+m]*Vv[w][m];
    }
    __syncthreads();
    if (t < 144) {
      dst[t] = acc;
      if (r >= 3 && r <= 11) ws[OFF_P2+(r-3)*144+t] = (float)acc;
      if (r == 7)  C128[t]=acc;
      if (r == 8)  C256[t]=acc;
      if (r == 9)  C512[t]=acc;
      if (r == 10) C1024[t]=acc;
      if (r == 11) C2048[t]=acc;
      if (r == 12) C4096[t]=acc;
    }
    if (r <= 7 && t >= 256 && t < 292) {
      Vv[w][i2] = ks;
      if (w == 0) Kd[(8-r)*12+i2] += ks;
      else if (w == 1) Kd[(9-r)*12+i2] += ks;
      else Kd[i2] += ks;
    }
    __syncthreads();
    double* tmp = src; src = dst; dst = tmp;    // src = M^(2^r)
  }
  if (t < 120) ws[OFF_K+t] = (float)Kd[t];
  if (t < 144) {
    ws[OFF_PQ+t]       = (float)C128[t];
    ws[OFF_PQ+144+t]   = (float)C256[t];
    ws[OFF_PW+t]       = (float)C512[t];
    ws[OFF_PW+144+t]   = (float)C1024[t];
    ws[OFF_PW+3*144+t] = (float)C2048[t];
    ws[OFF_PD+t]       = (t % 13 == 0) ? 1.f : 0.f;   // Pd[0]=I
    ws[OFF_PD+144+t]   = (float)C4096[t];
  }
  // round A: M^384=C128*C256 ; M^1536=C512*C1024 ; M^2560=C512*C2048
  if (t < 432) {
    int w=t/144, e=t%144, i=e/12, j=e%12;
    const double* Ap = (w==0) ? C128 : C512;
    const double* Bp = (w==0) ? C256 : ((w==1) ? C1024 : C2048);
    double s = 0.0;
#pragma unroll
    for (int m = 0; m < 12; ++m) s += Ap[i*12+m]*Bp[m*12+j];
    if (w==0) ws[OFF_PQ+2*144+e] = (float)s;
    else if (w==1) { D1536[e]=s; ws[OFF_PW+2*144+e] = (float)s; }
    else ws[OFF_PW+4*144+e] = (float)s;
  }
  __syncthreads();
  // round B: M^3072=C1024*C2048 ; M^3584=D1536*C2048
  if (t < 288) {
    int w=t/144, e=t%144, i=e/12, j=e%12;
    const double* Ap = (w==0) ? C1024 : D1536;
    double s = 0.0;
#pragma unroll
    for (int m = 0; m < 12; ++m) s += Ap[i*12+m]*C2048[m*12+j];
    ws[OFF_PW+((w==0)?5:6)*144+e] = (float)s;
  }
  // Pd chain: src=M^4096; Pd[j]=Pd[j-1]*M^4096
  for (int j = 2; j < NLOOK; ++j) {
    double acc = 0.0;
    if (t < 144) {
      int i=t/12, jj=t%12;
#pragma unroll
      for (int m = 0; m < 12; ++m) acc += src[i*12+m]*C4096[m*12+jj];
    }
    __syncthreads();
    if (t < 144) { dst[t] = acc; ws[OFF_PD+j*144+t] = (float)acc; }
    __syncthreads();
    double* tmp = src; src = dst; dst = tmp;
  }
}

// K1: per-block aggregate only. Wave-shfl REDUCTION (aligned combines stay
// within-wave -- correct, unlike a scan) + 3-level LDS tree over wave totals.
__global__ void __launch_bounds__(BLK) block_agg(
    const float* cons, const float* __restrict__ To,
    const float* __restrict__ x0, float* agg) {
  __shared__ float Tw[96], Ta[48], Tb[24];
  int k = threadIdx.x, b = blockIdx.x;
  int g = b*BLK + k, base = g*CH;
  float v[12];
  if (g <= LASTFULL) {
    const float4* tp = reinterpret_cast<const float4*>(To + base);
    float4 ta = tp[0], tb = tp[1];
    float tos[9] = {ta.x,ta.y,ta.z,ta.w, tb.x,tb.y,tb.z,tb.w, To[base+8]};
    fold_chunk(cons, tos, v);
  } else {
#pragma unroll
    for (int i = 0; i < 12; ++i) v[i] = 0.f;
  }
  if (g == 0) {                       // fold x0: v += M^8 x0
    float xi[12];
#pragma unroll
    for (int i = 0; i < 12; ++i) xi[i] = x0[i];
    mv_acc(cons + OFF_P2, xi, v);
  }
  // wave-local inclusive scan (lane 63 -> wave total; mid-lane values unused)
#pragma unroll
  for (int l = 0; l < 6; ++l) {
    int off = 1 << l;
    float nb[12];
#pragma unroll
    for (int i = 0; i < 12; ++i) nb[i] = __shfl_up(v[i], (unsigned)off, 64);
    if ((k & 63) >= off) mv_acc(cons + OFF_P2 + l*144, nb, v);
  }
  if ((k & 63) == 63) {
#pragma unroll
    for (int i = 0; i < 12; ++i) Tw[(k>>6)*12 + i] = v[i];
  }
  __syncthreads();
  if (k < 48) {                       // pair combine: right len 64 -> P2[6]
    int p = k/12, i = k%12;
    const float* L = Tw + 2*p*12;
    float acc = Tw[(2*p+1)*12 + i];
    const float4* Pr = reinterpret_cast<const float4*>(cons + OFF_P2 + 6*144 + i*12);
    float4 p0=Pr[0], p1=Pr[1], p2=Pr[2];
    acc = FMA4(p0, L[0],L[1],L[2],L[3], acc);
    acc = FMA4(p1, L[4],L[5],L[6],L[7], acc);
    acc = FMA4(p2, L[8],L[9],L[10],L[11], acc);
    Ta[p*12+i] = acc;
  }
  __syncthreads();
  if (k < 24) {                       // right len 128 -> P2[7]
    int q = k/12, i = k%12;
    const float* L = Ta + 2*q*12;
    float acc = Ta[(2*q+1)*12 + i];
    const float4* Pr = reinterpret_cast<const float4*>(cons + OFF_P2 + 7*144 + i*12);
    float4 p0=Pr[0], p1=Pr[1], p2=Pr[2];
    acc = FMA4(p0, L[0],L[1],L[2],L[3], acc);
    acc = FMA4(p1, L[4],L[5],L[6],L[7], acc);
    acc = FMA4(p2, L[8],L[9],L[10],L[11], acc);
    Tb[q*12+i] = acc;
  }
  __syncthreads();
  if (k < 12) {                       // right len 256 -> P2[8]
    float acc = Tb[12 + k];
    const float4* Pr = reinterpret_cast<const float4*>(cons + OFF_P2 + 8*144 + k*12);
    float4 p0=Pr[0], p1=Pr[1], p2=Pr[2];
    acc = FMA4(p0, Tb[0],Tb[1],Tb[2],Tb[3], acc);
    acc = FMA4(p1, Tb[4],Tb[5],Tb[6],Tb[7], acc);
    acc = FMA4(p2, Tb[8],Tb[9],Tb[10],Tb[11], acc);
    agg[b*12 + k] = acc;
  }
}

#define ROWX(i, MA,MB,MC) xn[i] = FMA4(MC, x[8],x[9],x[10],x[11], \
    FMA4(MB, x[4],x[5],x[6],x[7], FMA4(MA, x[0],x[1],x[2],x[3], \
    fmaf(bv[i],ton,fmaf(av[i],tot,cv[i])))));

// K2: fold + LDS Hillis-Steele scan (R4-proven) + lookback + hierarchical
// prefix + 8-step expand with M in named float4 registers.
__global__ void __launch_bounds__(BLK, 2) scan_expand(
    const float* cons, const float* __restrict__ To,
    const float* __restrict__ x0, float* __restrict__ out) {
  __shared__ float lw[BLK*13];
  __shared__ float partl[NLOOK*12];
  __shared__ float Xs[12];
  __shared__ float Xw[96];
  __shared__ float Xq[384];
  int k = threadIdx.x, b = blockIdx.x;
  int g = b*BLK + k, base = g*CH;
  bool active = (g < NCHUNK), fullc = (g <= LASTFULL);
  float to[9];
  if (active) {
    const float4* tp = reinterpret_cast<const float4*>(To + base);
    float4 ta = tp[0], tb = tp[1];
    to[0]=ta.x; to[1]=ta.y; to[2]=ta.z; to[3]=ta.w;
    to[4]=tb.x; to[5]=tb.y; to[6]=tb.z; to[7]=tb.w;
    to[8] = fullc ? To[base+8] : 0.f;
  }
  float v[12];
  if (fullc) fold_chunk(cons, to, v);
  else {
#pragma unroll
    for (int i = 0; i < 12; ++i) v[i] = 0.f;
  }
  if (g == 0) {
    float xi[12];
#pragma unroll
    for (int i = 0; i < 12; ++i) xi[i] = x0[i];
    mv_acc(cons + OFF_P2, xi, v);
  }
#pragma unroll
  for (int i = 0; i < 12; ++i) lw[k*13+i] = v[i];
  // truncated lookback partials: partl[j*12+i] = (M^(4096j) * agg[b-1-j])_i
  if (k < NLOOK*12) {
    int j = k/12, i = k%12, src = b - 1 - j;
    float acc = 0.f;
    if (src >= 0) {
      const float4* Pr = reinterpret_cast<const float4*>(cons + OFF_PD + j*144 + i*12);
      const float4* Ar = reinterpret_cast<const float4*>(cons + OFF_AGG + src*12);
      float4 p0=Pr[0], p1=Pr[1], p2=Pr[2], a0=Ar[0], a1=Ar[1], a2=Ar[2];
      acc = FMA4(p0, a0.x,a0.y,a0.z,a0.w, acc);
      acc = FMA4(p1, a1.x,a1.y,a1.z,a1.w, acc);
      acc = FMA4(p2, a2.x,a2.y,a2.z,a2.w, acc);
    }
    partl[k] = acc;
  }
  __syncthreads();
  if (k < 12) {
    float s = 0.f;
#pragma unroll
    for (int j = 0; j < NLOOK; ++j) s += partl[j*12 + k];
    Xs[k] = s;                        // visible after scan's barriers
  }
  // 9-level LDS Hillis-Steele inclusive scan (proven in R4)
#pragma unroll
  for (int l = 0; l < 9; ++l) {
    int off = 1 << l;
    bool act = (k >= off);
    float nb[12];
    if (act) {
#pragma unroll
      for (int i = 0; i < 12; ++i) nb[i] = lw[(k-off)*13 + i];
    }
    __syncthreads();
    if (act) {
      mv_acc(cons + OFF_P2 + l*144, nb, v);
#pragma unroll
      for (int i = 0; i < 12; ++i) lw[k*13+i] = v[i];
    }
    __syncthreads();
  }
  float sp[12];                       // S_{k-1}
  if (k > 0) {
#pragma unroll
    for (int i = 0; i < 12; ++i) sp[i] = lw[(k-1)*13 + i];
  } else {
#pragma unroll
    for (int i = 0; i < 12; ++i) sp[i] = 0.f;
  }
  // stage A: Xw[w] = M^(512w)*Xs, w=0..7
  if (k < 96) {
    int w = k/12, i = k%12;
    float acc;
    if (w == 0) acc = Xs[i];
    else {
      const float4* Wr = reinterpret_cast<const float4*>(cons + OFF_PW + (w-1)*144 + i*12);
      float4 p0=Wr[0], p1=Wr[1], p2=Wr[2];
      acc = FMA4(p0, Xs[0],Xs[1],Xs[2],Xs[3], 0.f);
      acc = FMA4(p1, Xs[4],Xs[5],Xs[6],Xs[7], acc);
      acc = FMA4(p2, Xs[8],Xs[9],Xs[10],Xs[11], acc);
    }
    Xw[w*12 + i] = acc;
  }
  __syncthreads();
  // stage B: Xq[q] = M^(128(q&3))*Xw[q>>2], q=0..31
  if (k < 384) {
    int q = k/12, i = k%12, d = q & 3;
    const float* xw = Xw + (q>>2)*12;
    float acc;
    if (d == 0) acc = xw[i];
    else {
      const float4* Qr = reinterpret_cast<const float4*>(cons + OFF_PQ + (d-1)*144 + i*12);
      float4 p0=Qr[0], p1=Qr[1], p2=Qr[2];
      acc = FMA4(p0, xw[0],xw[1],xw[2],xw[3], 0.f);
      acc = FMA4(p1, xw[4],xw[5],xw[6],xw[7], acc);
      acc = FMA4(p2, xw[8],xw[9],xw[10],xw[11], acc);
    }
    Xq[q*12 + i] = acc;
  }
  __syncthreads();
  // per-thread: vp = M^(8(k&15)) * Xq[k>>4]
  float vp[12];
  {
    const float* xq = Xq + (k>>4)*12;
#pragma unroll
    for (int i = 0; i < 12; ++i) vp[i] = xq[i];
  }
#pragma unroll
  for (int l = 0; l < 4; ++l) {
    if ((k >> l) & 1) {
      float vn[12];
#pragma unroll
      for (int i = 0; i < 12; ++i) vn[i] = 0.f;
      mv_acc(cons + OFF_P2 + l*144, vp, vn);
#pragma unroll
      for (int i = 0; i < 12; ++i) vp[i] = vn[i];
    }
  }
  float x[12];
  if (k > 0) {
#pragma unroll
    for (int i = 0; i < 12; ++i) x[i] = vp[i] + sp[i];
  } else {
#pragma unroll
    for (int i = 0; i < 12; ++i) x[i] = vp[i] + (b == 0 ? x0[i] : 0.f);
  }
  if (b == 0 && k == 0) {
#pragma unroll
    for (int i = 0; i < 12; ++i) out[i] = x0[i];     // row 0
  }
  if (!active) return;
  // M + c/al/be into registers once; 8 steps; float4 row stores
  float cv[12], av[12], bv[12];
  {
    const float4* Cq = reinterpret_cast<const float4*>(cons + OFF_C);
    const float4* Aq = reinterpret_cast<const float4*>(cons + OFF_AL);
    const float4* Bq = reinterpret_cast<const float4*>(cons + OFF_BE);
    float4 q;
    q=Cq[0]; cv[0]=q.x;cv[1]=q.y;cv[2]=q.z;cv[3]=q.w;
    q=Cq[1]; cv[4]=q.x;cv[5]=q.y;cv[6]=q.z;cv[7]=q.w;
    q=Cq[2]; cv[8]=q.x;cv[9]=q.y;cv[10]=q.z;cv[11]=q.w;
    q=Aq[0]; av[0]=q.x;av[1]=q.y;av[2]=q.z;av[3]=q.w;
    q=Aq[1]; av[4]=q.x;av[5]=q.y;av[6]=q.z;av[7]=q.w;
    q=Aq[2]; av[8]=q.x;av[9]=q.y;av[10]=q.z;av[11]=q.w;
    q=Bq[0]; bv[0]=q.x;bv[1]=q.y;bv[2]=q.z;bv[3]=q.w;
    q=Bq[1]; bv[4]=q.x;bv[5]=q.y;bv[6]=q.z;bv[7]=q.w;
    q=Bq[2]; bv[8]=q.x;bv[9]=q.y;bv[10]=q.z;bv[11]=q.w;
  }
  const float4* Mq = reinterpret_cast<const float4*>(cons + OFF_M);
  float4 m00=Mq[0],  m01=Mq[1],  m02=Mq[2],  m03=Mq[3],  m04=Mq[4],  m05=Mq[5];
  float4 m06=Mq[6],  m07=Mq[7],  m08=Mq[8],  m09=Mq[9],  m10=Mq[10], m11=Mq[11];
  float4 m12=Mq[12], m13=Mq[13], m14=Mq[14], m15=Mq[15], m16=Mq[16], m17=Mq[17];
  float4 m18=Mq[18], m19=Mq[19], m20=Mq[20], m21=Mq[21], m22=Mq[22], m23=Mq[23];
  float4 m24=Mq[24], m25=Mq[25], m26=Mq[26], m27=Mq[27], m28=Mq[28], m29=Mq[29];
  float4 m30=Mq[30], m31=Mq[31], m32=Mq[32], m33=Mq[33], m34=Mq[34], m35=Mq[35];
#pragma unroll
  for (int s = 0; s < CH; ++s) {
    int tt = base + s;
    if (tt >= S_STEPS) break;
    float tot = to[s], ton = to[s+1];
    float xn[12];
    ROWX(0,  m00,m01,m02)  ROWX(1,  m03,m04,m05)
    ROWX(2,  m06,m07,m08)  ROWX(3,  m09,m10,m11)
    ROWX(4,  m12,m13,m14)  ROWX(5,  m15,m16,m17)
    ROWX(6,  m18,m19,m20)  ROWX(7,  m21,m22,m23)
    ROWX(8,  m24,m25,m26)  ROWX(9,  m27,m28,m29)
    ROWX(10, m30,m31,m32)  ROWX(11, m33,m34,m35)
    float4* op = reinterpret_cast<float4*>(out + (size_t)(tt+1)*12);
    op[0] = make_float4(xn[0],xn[1],xn[2],xn[3]);
    op[1] = make_float4(xn[4],xn[5],xn[6],xn[7]);
    op[2] = make_float4(xn[8],xn[9],xn[10],xn[11]);
#pragma unroll
    for (int i = 0; i < 12; ++i) x[i] = xn[i];
  }
}

extern "C" void kernel_launch(void* const* d_in, const int* in_sizes, int n_in,
                              void* d_out, int out_size, void* d_ws, size_t ws_size,
                              hipStream_t stream) {
  const float* t_eval    = (const float*)d_in[0];
  const float* x0        = (const float*)d_in[1];
  const float* A         = (const float*)d_in[2];
  const float* B         = (const float*)d_in[3];
  const float* To        = (const float*)d_in[4];
  const float* loads_raw = (const float*)d_in[5];
  const float* areas     = (const float*)d_in[6];
  float* out = (float*)d_out;
  float* ws  = (float*)d_ws;

  setup_kernel<<<1, 512, 0, stream>>>(t_eval, A, B, loads_raw, areas, ws);
  block_agg<<<NB, BLK, 0, stream>>>(ws, To, x0, ws + OFF_AGG);
  scan_expand<<<NB, BLK, 0, stream>>>(ws, To, x0, out);
}

// Round 8
// 131.817 us; speedup vs baseline: 1.4186x; 1.0284x over previous
//
#include <hip/hip_runtime.h>
#include <math.h>

// RC thermal model: x' = A x + b0*To(t) + Bq, RK4 h=30, T=1e6 steps.
// Per step: x_{t+1} = M x_t + c + al*To[t] + be*To[t+1].
// R8 diagnosis: R6's FETCH_SIZE=2.4GB + VGPR=40 = per-thread arrays demoted
// to SCRATCH. Cause: data-dependent `break` inside #pragma unroll step loop
// blocks full unroll -> dynamic indexing -> arrays in private memory.
// Fix: constant-trip loops everywhere, predicated stores, no break.
// Structure: 3 plain launches (no cooperative -- R7's coop launch of 977
// blocks was rejected, capacity ~768). CH=4, BLK=256, 977 blocks.
// K1: fold + wave shfl-scan + LDS tree -> 1024-step block aggregates.
// K2: fold + wave shfl-scan (exclusive) + truncated 64-block lookback
// (M^65536~3e-9) + merged prefix x = M^(4j)(M^(256w)Xstart + P_w) + se
// + 4-step expand, all matrices read per-use as b128 (L1-resident).

#define S_STEPS 999999
#define CH      4
#define BLK     256
#define NB      977          // 977*256*4 = 1,000,448 >= S_STEPS
#define NCHUNK  250000       // active chunks (last partial: 3 steps)
#define LASTFULL 249998      // g <= LASTFULL: To[4g+4] in bounds

// ws float offsets (16B-aligned)
#define OFF_M   0            // 144: M
#define OFF_C   144          // 12
#define OFF_AL  156          // 12
#define OFF_BE  168          // 12
#define OFF_K   192          // 72: K cols [col][12], col0 = const (6 cols)
#define OFF_P2  264          // 8*144: P2[l] = M^(4*2^l), l=0..7 (M^4..M^512)
#define OFF_PA  1416         // 2*144: PA[0]=M^192 (unused), PA[1]=M^768
#define OFF_PL  1704         // 3*144: M^1024, M^2048, M^3072
#define OFF_PD  2136         // 16*144: M^(4096j), j=0..15 (Pd[0]=I)
#define OFF_AGG 4440         // 977*12 block aggregates (end 16164 ~ 65 KB)

#define FMA4(Q,a,b,c,d,acc) fmaf((Q).w,(d),fmaf((Q).z,(c),fmaf((Q).y,(b),fmaf((Q).x,(a),(acc)))))

// y += P(12x12 row-major, 16B-aligned) * x
__device__ __forceinline__ void mv_acc(const float* Pf, const float* x, float* y) {
  const float4* P = reinterpret_cast<const float4*>(Pf);
#pragma unroll
  for (int i = 0; i < 12; ++i) {
    float4 a = P[3*i], b = P[3*i+1], c = P[3*i+2];
    y[i] = FMA4(c, x[8],x[9],x[10],x[11],
            FMA4(b, x[4],x[5],x[6],x[7],
             FMA4(a, x[0],x[1],x[2],x[3], y[i])));
  }
}

// dot(P row (16B-aligned), xv[0..11] scalars)
__device__ __forceinline__ float rowdot(const float* Prow, const float* xv) {
  const float4* P = reinterpret_cast<const float4*>(Prow);
  float4 a = P[0], b = P[1], c = P[2];
  return FMA4(c, xv[8],xv[9],xv[10],xv[11],
          FMA4(b, xv[4],xv[5],xv[6],xv[7],
           FMA4(a, xv[0],xv[1],xv[2],xv[3], 0.f)));
}

// v = K[:,0] + sum_{s=0..4} K[:,s+1]*tos[s]
__device__ __forceinline__ void fold_chunk(const float* __restrict__ cons,
                                           const float* tos, float* v) {
  const float4* Kq = reinterpret_cast<const float4*>(cons + OFF_K);
  float4 c0=Kq[0], c1=Kq[1], c2=Kq[2];
  v[0]=c0.x; v[1]=c0.y; v[2]=c0.z; v[3]=c0.w;
  v[4]=c1.x; v[5]=c1.y; v[6]=c1.z; v[7]=c1.w;
  v[8]=c2.x; v[9]=c2.y; v[10]=c2.z; v[11]=c2.w;
#pragma unroll
  for (int s = 0; s < 5; ++s) {
    float ts = tos[s];
    float4 ka=Kq[3*(s+1)], kb=Kq[3*(s+1)+1], kc=Kq[3*(s+1)+2];
    v[0]=fmaf(ka.x,ts,v[0]); v[1]=fmaf(ka.y,ts,v[1]); v[2]=fmaf(ka.z,ts,v[2]); v[3]=fmaf(ka.w,ts,v[3]);
    v[4]=fmaf(kb.x,ts,v[4]); v[5]=fmaf(kb.y,ts,v[5]); v[6]=fmaf(kb.z,ts,v[6]); v[7]=fmaf(kb.w,ts,v[7]);
    v[8]=fmaf(kc.x,ts,v[8]); v[9]=fmaf(kc.y,ts,v[9]); v[10]=fmaf(kc.z,ts,v[10]); v[11]=fmaf(kc.w,ts,v[11]);
  }
}

__global__ void __launch_bounds__(512) setup_kernel(
    const float* __restrict__ t_eval, const float* __restrict__ A,
    const float* __restrict__ Bm, const float* __restrict__ loads_raw,
    const float* __restrict__ areas, float* ws) {
  __shared__ double H1[144], H2[144], H3[144], H4[144], Md[144];
  __shared__ double Qa[144], Qb[144];
  __shared__ double C64[144], C128[144], C256[144], C512[144];
  __shared__ double C1024[144], C2048[144], C4096[144];
  __shared__ double cd[12], ald[12], bed[12], b0d[12], bqd[12];
  __shared__ double Vv[3][12], Kd[72];
  int t = threadIdx.x;
  double h = (double)t_eval[1] - (double)t_eval[0];
  if (t < 144) H1[t] = h * (double)A[t];
  if (t < 12) {
    b0d[t] = (double)Bm[t*11];
    double s = 0.0;
    for (int r = 0; r < 10; ++r) {
      double gq = 50.0 / (1.0 + exp(-(double)loads_raw[10 + r]));
      s += (double)Bm[t*11 + 1 + r] * (gq * (double)areas[r]);
    }
    bqd[t] = s;
  }
  if (t < 72) Kd[t] = 0.0;
  __syncthreads();
  if (t < 144) {                              // H2 = H1*H1
    int i=t/12, j=t%12; double s=0.0;
#pragma unroll
    for (int m = 0; m < 12; ++m) s += H1[i*12+m]*H1[m*12+j];
    H2[t]=s;
  }
  __syncthreads();
  if (t < 288) {                              // H3 = H2*H1 | H4 = H2*H2
    int w=t/144, e=t%144, i=e/12, j=e%12;
    const double* Bp = w ? H2 : H1;
    double s = 0.0;
#pragma unroll
    for (int m = 0; m < 12; ++m) s += H2[i*12+m]*Bp[m*12+j];
    (w ? H4 : H3)[e] = s;
  }
  __syncthreads();
  if (t < 12) {
    double hb=0,h2b=0,h3b=0,hb0=0,h2b0=0,h3b0=0;
#pragma unroll
    for (int m = 0; m < 12; ++m) {
      hb  += H1[t*12+m]*bqd[m]; h2b  += H2[t*12+m]*bqd[m]; h3b  += H3[t*12+m]*bqd[m];
      hb0 += H1[t*12+m]*b0d[m]; h2b0 += H2[t*12+m]*b0d[m]; h3b0 += H3[t*12+m]*b0d[m];
    }
    double h6 = h / 6.0;
    cd[t]  = h6*(6.0*bqd[t] + 3.0*hb + h2b + 0.25*h3b);
    ald[t] = h6*(3.0*b0d[t] + 2.0*hb0 + 0.75*h2b0 + 0.25*h3b0);
    bed[t] = h6*(3.0*b0d[t] + hb0 + 0.25*h2b0);
    Vv[0][t]=ald[t]; Vv[1][t]=bed[t]; Vv[2][t]=cd[t];
    // it=0 K contributions (CH=4): col4 += al, col5 += be, col0 += c
    Kd[48+t] += ald[t]; Kd[60+t] += bed[t]; Kd[t] += cd[t];
  }
  if (t >= 144 && t < 288) {
    int e=t-144, i=e/12, j=e%12;
    Md[e] = (i==j ? 1.0 : 0.0) + H1[e] + 0.5*H2[e] + H3[e]/6.0 + H4[e]/24.0;
  }
  __syncthreads();
  if (t < 144) { ws[OFF_M+t] = (float)Md[t]; Qa[t] = Md[t]; }
  if (t < 12) {
    ws[OFF_C+t]=(float)cd[t]; ws[OFF_AL+t]=(float)ald[t]; ws[OFF_BE+t]=(float)bed[t];
  }
  __syncthreads();
  // chain r=1..12: src=M^(2^(r-1)) -> dst=M^(2^r). Overlapped K rounds
  // r=1..3 (threads 256..291): Vv=M^r*{al,be,c}; Kd cols (4-r),(5-r),0.
  double* src = Qa; double* dst = Qb;
  for (int r = 1; r <= 12; ++r) {
    double acc = 0.0, ks = 0.0;
    if (t < 144) {
      int i=t/12, j=t%12;
#pragma unroll
      for (int m = 0; m < 12; ++m) acc += src[i*12+m]*src[m*12+j];
    }
    int w=0, i2=0;
    if (r <= 3 && t >= 256 && t < 292) {
      w=(t-256)/12; i2=(t-256)%12;
#pragma unroll
      for (int m = 0; m < 12; ++m) ks += Md[i2*12+m]*Vv[w][m];
    }
    __syncthreads();
    if (t < 144) {
      dst[t] = acc;
      if (r >= 2 && r <= 9) ws[OFF_P2+(r-2)*144+t] = (float)acc;  // M^4..M^512
      if (r == 6)  C64[t]=acc;
      if (r == 7)  C128[t]=acc;
      if (r == 8)  C256[t]=acc;
      if (r == 9)  C512[t]=acc;
      if (r == 10) C1024[t]=acc;
      if (r == 11) C2048[t]=acc;
      if (r == 12) C4096[t]=acc;
    }
    if (r <= 3 && t >= 256 && t < 292) {
      Vv[w][i2] = ks;
      if (w == 0) Kd[(4-r)*12+i2] += ks;
      else if (w == 1) Kd[(5-r)*12+i2] += ks;
      else Kd[i2] += ks;
    }
    __syncthreads();
    double* tmp = src; src = dst; dst = tmp;    // src = M^(2^r)
  }
  if (t < 72) ws[OFF_K+t] = (float)Kd[t];
  if (t < 144) {
    ws[OFF_PL+t]     = (float)C1024[t];
    ws[OFF_PL+144+t] = (float)C2048[t];
    ws[OFF_PD+t]     = (t % 13 == 0) ? 1.f : 0.f;   // Pd[0]=I
    ws[OFF_PD+144+t] = (float)C4096[t];
  }
  // products: M^192=C64*C128 ; M^768=C256*C512 ; M^3072=C1024*C2048
  if (t < 432) {
    int w=t/144, e=t%144, i=e/12, j=e%12;
    const double* Ap = (w==0) ? C64 : ((w==1) ? C256 : C1024);
    const double* Bp = (w==0) ? C128 : ((w==1) ? C512 : C2048);
    double s = 0.0;
#pragma unroll
    for (int m = 0; m < 12; ++m) s += Ap[i*12+m]*Bp[m*12+j];
    if (w==0) ws[OFF_PA+e] = (float)s;
    else if (w==1) ws[OFF_PA+144+e] = (float)s;
    else ws[OFF_PL+2*144+e] = (float)s;
  }
  // Pd chain: Pd[j] = Pd[j-1]*M^4096, j=2..15 (src = M^4096)
  for (int j = 2; j < 16; ++j) {
    double acc = 0.0;
    if (t < 144) {
      int i=t/12, jj=t%12;
#pragma unroll
      for (int m = 0; m < 12; ++m) acc += src[i*12+m]*C4096[m*12+jj];
    }
    __syncthreads();
    if (t < 144) { dst[t] = acc; ws[OFF_PD+j*144+t] = (float)acc; }
    __syncthreads();
    double* tmp = src; src = dst; dst = tmp;
  }
}

// K1: block aggregate (1024 steps) = wave shfl-scan (6 levels, aligned
// wave segments -- R6-proven) + 2-level LDS tree over 4 wave totals.
__global__ void __launch_bounds__(BLK, 4) block_agg(
    const float* __restrict__ cons, const float* __restrict__ To,
    const float* __restrict__ x0, float* __restrict__ agg) {
  __shared__ __align__(16) float Tw[48], Ta[24];
  int k = threadIdx.x, b = blockIdx.x;
  int g = b*BLK + k, base = g*CH;
  bool fullc = (g <= LASTFULL);
  float to_[5];
#pragma unroll
  for (int i = 0; i < 5; ++i) to_[i] = 0.f;
  if (fullc) {
    const float4* tp = reinterpret_cast<const float4*>(To + base);
    float4 ta = tp[0];
    to_[0]=ta.x; to_[1]=ta.y; to_[2]=ta.z; to_[3]=ta.w;
    to_[4]=To[base+4];
  }
  float v[12];
  if (fullc) fold_chunk(cons, to_, v);
  else {
#pragma unroll
    for (int i = 0; i < 12; ++i) v[i] = 0.f;
  }
  if (g == 0) {                      // fold x0 into chunk 0: v += M^4 x0
    float xi[12];
#pragma unroll
    for (int i = 0; i < 12; ++i) xi[i] = x0[i];
    mv_acc(cons + OFF_P2, xi, v);
  }
  int j = k & 63;
#pragma unroll
  for (int l = 0; l < 6; ++l) {      // in-wave inclusive scan
    int off = 1 << l;
    float nb[12];
#pragma unroll
    for (int i = 0; i < 12; ++i) nb[i] = __shfl_up(v[i], (unsigned)off, 64);
    if (j >= off) mv_acc(cons + OFF_P2 + l*144, nb, v);
  }
  if (j == 63) {
#pragma unroll
    for (int i = 0; i < 12; ++i) Tw[(k>>6)*12 + i] = v[i];
  }
  __syncthreads();
  if (k < 24) {                      // (T0,T1),(T2,T3): M^256*left + right
    int p = k/12, comp = k - p*12;
    Ta[k] = rowdot(cons + OFF_P2 + 6*144 + comp*12, Tw + 2*p*12)
          + Tw[(2*p+1)*12 + comp];
  }
  __syncthreads();
  if (k < 12) {                      // M^512*Ta0 + Ta1
    agg[b*12 + k] = rowdot(cons + OFF_P2 + 7*144 + k*12, Ta) + Ta[12 + k];
  }
}

// K2: fold + wave scan (exclusive) + truncated lookback + merged prefix
// apply + 4-step expand (no break; predicated stores).
__global__ void __launch_bounds__(BLK, 2) scan_expand(
    const float* __restrict__ cons, const float* __restrict__ To,
    const float* __restrict__ x0, const float* __restrict__ agg,
    float* __restrict__ out) {
  __shared__ __align__(16) float Tw[48];      // wave totals
  __shared__ __align__(16) float Pw[48];      // wave exclusive prefixes
  __shared__ __align__(16) float lkb[64*12];  // lookback stage-1 partials
  __shared__ __align__(16) float yv[16*12];
  __shared__ __align__(16) float zv[16*12];
  __shared__ __align__(16) float Xs[12];
  __shared__ __align__(16) float Qw[48];      // M^(256w)*Xs + Pw
  int k = threadIdx.x, b = blockIdx.x;
  int g = b*BLK + k, base = g*CH;
  bool active = (g < NCHUNK), fullc = (g <= LASTFULL);
  float to_[5];
#pragma unroll
  for (int i = 0; i < 5; ++i) to_[i] = 0.f;
  if (active) {
    const float4* tp = reinterpret_cast<const float4*>(To + base);
    float4 ta = tp[0];
    to_[0]=ta.x; to_[1]=ta.y; to_[2]=ta.z; to_[3]=ta.w;
    to_[4] = fullc ? To[base+4] : 0.f;
  }
  float v[12];
  if (fullc) fold_chunk(cons, to_, v);
  else {
#pragma unroll
    for (int i = 0; i < 12; ++i) v[i] = 0.f;
  }
  if (g == 0) {
    float xi[12];
#pragma unroll
    for (int i = 0; i < 12; ++i) xi[i] = x0[i];
    mv_acc(cons + OFF_P2, xi, v);
  }
  int j = k & 63, w = k >> 6;
#pragma unroll
  for (int l = 0; l < 6; ++l) {      // in-wave inclusive scan
    int off = 1 << l;
    float nb[12];
#pragma unroll
    for (int i = 0; i < 12; ++i) nb[i] = __shfl_up(v[i], (unsigned)off, 64);
    if (j >= off) mv_acc(cons + OFF_P2 + l*144, nb, v);
  }
  float se[12];                      // exclusive in-wave scan
#pragma unroll
  for (int i = 0; i < 12; ++i) {
    float u = __shfl_up(v[i], 1u, 64);
    se[i] = (j == 0) ? 0.f : u;
  }
  if (j == 63) {
#pragma unroll
    for (int i = 0; i < 12; ++i) Tw[w*12 + i] = v[i];
  }
  // lookback stage 1 (before barrier): slot=4i+jj:
  // lkb[slot] = M^(1024jj)*agg[b-1-slot]
#pragma unroll
  for (int r = 0; r < 3; ++r) {
    int idx = k + r*BLK;             // 768 = 3*BLK
    int slot = idx / 12, comp = idx - slot*12;
    int src = b - 1 - slot;
    float acc = 0.f;
    if (src >= 0) {
      int jj = slot & 3;
      const float* ag = agg + src*12;
      acc = (jj == 0) ? ag[comp]
          : rowdot(cons + OFF_PL + (jj-1)*144 + comp*12, ag);
    }
    lkb[idx] = acc;
  }
  __syncthreads();
  // yv[i] = sum_jj lkb[4i+jj]  (k<192)  |  Pw: P0=0, P1=T0  (k in [192,216))
  if (k < 192) {
    int i = k/12, comp = k - i*12;
    yv[k] = lkb[(4*i)*12+comp] + lkb[(4*i+1)*12+comp]
          + lkb[(4*i+2)*12+comp] + lkb[(4*i+3)*12+comp];
  } else if (k < 216) {
    int q = k - 192;                 // 0..23
    if (q < 12) Pw[q] = 0.f;         // P0
    else Pw[q] = Tw[q-12];           // P1 = T0
  }
  __syncthreads();
  // zv[i] = M^(4096i)*yv[i] (k<192) | P2 = M^256*P1 + T1 (k in [192,204))
  if (k < 192) {
    int i = k/12, comp = k - i*12;
    zv[k] = (i == 0) ? yv[comp]
          : rowdot(cons + OFF_PD + i*144 + comp*12, yv + i*12);
  } else if (k < 204) {
    int comp = k - 192;
    Pw[24+comp] = rowdot(cons + OFF_P2 + 6*144 + comp*12, Pw+12) + Tw[12+comp];
  }
  __syncthreads();
  // Xs = sum_i zv[i] (k<12) | P3 = M^256*P2 + T2 (k in [192,204))
  if (k < 12) {
    float s = 0.f;
#pragma unroll
    for (int i = 0; i < 16; ++i) s += zv[i*12 + k];
    Xs[k] = s;
  } else if (k >= 192 && k < 204) {
    int comp = k - 192;
    Pw[36+comp] = rowdot(cons + OFF_P2 + 6*144 + comp*12, Pw+24) + Tw[24+comp];
  }
  __syncthreads();
  // Qw[w] = M^(256w)*Xs + Pw[w]  (w=0..3; matrices I, M^256, M^512, M^768)
  if (k < 48) {
    int ww = k/12, comp = k - ww*12;
    float acc;
    if (ww == 0) acc = Xs[comp];
    else if (ww == 1) acc = rowdot(cons + OFF_P2 + 6*144 + comp*12, Xs);
    else if (ww == 2) acc = rowdot(cons + OFF_P2 + 7*144 + comp*12, Xs);
    else acc = rowdot(cons + OFF_PA + 144 + comp*12, Xs);
    Qw[k] = acc + Pw[k];
  }
  __syncthreads();
  if (!active) return;               // all barriers done
  // per-thread: x = M^(4j)*Qw[w] + se   (bits of j, P2[0..5])
  float x[12];
#pragma unroll
  for (int i = 0; i < 12; ++i) x[i] = Qw[w*12 + i];
#pragma unroll
  for (int l = 0; l < 6; ++l) {
    if ((j >> l) & 1) {
      float vn[12];
#pragma unroll
      for (int i = 0; i < 12; ++i) vn[i] = 0.f;
      mv_acc(cons + OFF_P2 + l*144, x, vn);
#pragma unroll
      for (int i = 0; i < 12; ++i) x[i] = vn[i];
    }
  }
#pragma unroll
  for (int i = 0; i < 12; ++i) x[i] += se[i];
  if (b == 0 && k == 0) {
#pragma unroll
    for (int i = 0; i < 12; ++i) x[i] += x0[i];      // start state = x0
#pragma unroll
    for (int i = 0; i < 12; ++i) out[i] = x0[i];     // row 0
  }
  // expand: 4 unconditional steps, predicated stores (NO break)
  float cv[12], av[12], bv[12];
#pragma unroll
  for (int i = 0; i < 12; ++i) {
    cv[i] = cons[OFF_C + i]; av[i] = cons[OFF_AL + i]; bv[i] = cons[OFF_BE + i];
  }
  const float4* Mq = reinterpret_cast<const float4*>(cons + OFF_M);
#pragma unroll
  for (int s = 0; s < CH; ++s) {
    float tot = to_[s], ton = (s < CH-1) ? to_[s+1] : to_[4];
    float xn[12];
#pragma unroll
    for (int i = 0; i < 12; ++i) {
      float4 a = Mq[3*i], bq = Mq[3*i+1], c = Mq[3*i+2];
      xn[i] = FMA4(c, x[8],x[9],x[10],x[11],
               FMA4(bq, x[4],x[5],x[6],x[7],
                FMA4(a, x[0],x[1],x[2],x[3],
                 fmaf(bv[i],ton,fmaf(av[i],tot,cv[i])))));
    }
    int tt = base + s;
    if (tt < S_STEPS) {
      float4* op = reinterpret_cast<float4*>(out + (size_t)(tt+1)*12);
      op[0] = make_float4(xn[0],xn[1],xn[2],xn[3]);
      op[1] = make_float4(xn[4],xn[5],xn[6],xn[7]);
      op[2] = make_float4(xn[8],xn[9],xn[10],xn[11]);
    }
#pragma unroll
    for (int i = 0; i < 12; ++i) x[i] = xn[i];
  }
}

extern "C" void kernel_launch(void* const* d_in, const int* in_sizes, int n_in,
                              void* d_out, int out_size, void* d_ws, size_t ws_size,
                              hipStream_t stream) {
  const float* t_eval    = (const float*)d_in[0];
  const float* x0        = (const float*)d_in[1];
  const float* A         = (const float*)d_in[2];
  const float* B         = (const float*)d_in[3];
  const float* To        = (const float*)d_in[4];
  const float* loads_raw = (const float*)d_in[5];
  const float* areas     = (const float*)d_in[6];
  float* out = (float*)d_out;
  float* ws  = (float*)d_ws;

  setup_kernel<<<1, 512, 0, stream>>>(t_eval, A, B, loads_raw, areas, ws);
  block_agg<<<NB, BLK, 0, stream>>>(ws, To, x0, ws + OFF_AGG);
  scan_expand<<<NB, BLK, 0, stream>>>(ws, To, x0, ws + OFF_AGG, out);
}